// Round 1
// baseline (1630.048 us; speedup 1.0000x reference)
//
#include <hip/hip_runtime.h>
#include <math.h>

// Sizes fixed by the problem
#define BATCH 128
#define TT 512      // time steps
#define CIN 512
#define HID 256
#define GG 1024     // 4*HID

typedef _Float16 half2_t __attribute__((ext_vector_type(2)));
typedef _Float16 half8_t __attribute__((ext_vector_type(8)));
typedef float f32x4_t __attribute__((ext_vector_type(4)));

__device__ __forceinline__ float sigf(float x) { return 1.f / (1.f + __expf(-x)); }
__device__ __forceinline__ float tanhf_(float x) {
    float a = fabsf(x);
    float e = __expf(-2.f * a);
    float r = (1.f - e) / (1.f + e);
    return copysignf(r, x);
}
__device__ __forceinline__ float fdot2_(half2_t a, half2_t b, float c) {
#if __has_builtin(__builtin_amdgcn_fdot2)
    return __builtin_amdgcn_fdot2(a, b, c, false);
#else
    return c + (float)a.x * (float)b.x + (float)a.y * (float)b.y;
#endif
}

// Tiny prep: cast w1/w2/w_ih_f to f16, sum LSTM biases. grid 1024x256.
__global__ void prep_cast(const float* __restrict__ w1, const float* __restrict__ w2,
                          const float* __restrict__ wih, const float* __restrict__ bih,
                          const float* __restrict__ bhh,
                          _Float16* __restrict__ w1h, _Float16* __restrict__ w2h,
                          _Float16* __restrict__ wihh, float* __restrict__ bsum)
{
    const int i = blockIdx.x * 256 + threadIdx.x;
    if (i < 131072) w1h[i] = (_Float16)w1[i];
    if (i < 65536)  w2h[i] = (_Float16)w2[i];
    if (i < 262144) wihh[i] = (_Float16)wih[i];
    if (i < 1024)   bsum[i] = bih[i] + bhh[i];
}

// x[b][c=512][t=512] fp32 -> xt[b][t][c] f16 (64x64 LDS tiles, coalesced both sides)
__global__ __launch_bounds__(256) void cast_transpose_x(
    const float* __restrict__ x, _Float16* __restrict__ xt)
{
    const int b = blockIdx.z, c0 = blockIdx.y * 64, t0 = blockIdx.x * 64;
    __shared__ float tl[64][68];
    const float* xb = x + (size_t)b * CIN * TT;
    const int tid = threadIdx.x;
    const int lt = (tid & 15) * 4, lc = tid >> 4;
    #pragma unroll
    for (int r = 0; r < 4; ++r) {
        const int c = lc + r * 16;
        float4 v = *(const float4*)(xb + (size_t)(c0 + c) * TT + t0 + lt);
        tl[c][lt] = v.x; tl[c][lt + 1] = v.y; tl[c][lt + 2] = v.z; tl[c][lt + 3] = v.w;
    }
    __syncthreads();
    const int trow = tid >> 2, coff = (tid & 3) * 16;
    _Float16 o[16];
    #pragma unroll
    for (int i = 0; i < 16; ++i) o[i] = (_Float16)tl[coff + i][trow];
    _Float16* dst = xt + (size_t)b * TT * CIN + (size_t)(t0 + trow) * CIN + c0 + coff;
    *(float4*)dst = *(float4*)&o[0];
    *(float4*)(dst + 8) = *(float4*)&o[8];
}

// C[M,N](f16) = op( A[M,K]f16 . B[N,K]f16^T + bias ), K%32==0, M%128==0, N%128==0.
// 128x128 tile, 256 thr = 4 waves of 64x64, v_mfma_f32_16x16x32_f16.
// A/B-frag idx=lane&15, k=quad*8+j; D row=quad*4+reg, col=lane&15 (verified).
template <int RELU, int BIASROW>
__global__ __launch_bounds__(256, 4) void mfma_nt(
    const _Float16* __restrict__ A, const _Float16* __restrict__ B,
    const float* __restrict__ bias, _Float16* __restrict__ C,
    int M, int N, int K, long sA, long sB, long sC)
{
    __shared__ __align__(16) char smem[34816];
    _Float16 (*As)[40] = (_Float16(*)[40])smem;
    _Float16 (*Bs)[40] = (_Float16(*)[40])(smem + 10240);
    float (*Ct)[132] = (float(*)[132])smem;   // 64 x 132 fp32 (union w/ stage)

    const int nb = blockIdx.z;
    A += (size_t)nb * sA; B += (size_t)nb * sB; C += (size_t)nb * sC;
    const int m0 = blockIdx.y * 128, n0 = blockIdx.x * 128;
    const int tid = threadIdx.x;
    const int wave = tid >> 6, lane = tid & 63;
    const int quad = lane >> 4, l15 = lane & 15;
    const int wm = (wave >> 1) * 64, wn = (wave & 1) * 64;
    const int srow = tid >> 1, sko = (tid & 1) * 16;   // staging map

    f32x4_t acc[4][4];
    const f32x4_t zz = {0.f, 0.f, 0.f, 0.f};
    #pragma unroll
    for (int i = 0; i < 4; ++i)
        #pragma unroll
        for (int j = 0; j < 4; ++j) acc[i][j] = zz;

    for (int k0 = 0; k0 < K; k0 += 32) {
        {   // stage A,B tiles: 128 rows x 32 k each; thread = 16 f16 per tile
            const float4* ga = (const float4*)(A + (size_t)(m0 + srow) * K + k0 + sko);
            float4 a0 = ga[0], a1 = ga[1];
            const float4* gb = (const float4*)(B + (size_t)(n0 + srow) * K + k0 + sko);
            float4 b0 = gb[0], b1 = gb[1];
            *(float4*)&As[srow][sko] = a0; *(float4*)&As[srow][sko + 8] = a1;
            *(float4*)&Bs[srow][sko] = b0; *(float4*)&Bs[srow][sko + 8] = b1;
        }
        __syncthreads();
        half8_t af[4], bf[4];
        #pragma unroll
        for (int i = 0; i < 4; ++i) af[i] = *(const half8_t*)&As[wm + i * 16 + l15][quad * 8];
        #pragma unroll
        for (int j = 0; j < 4; ++j) bf[j] = *(const half8_t*)&Bs[wn + j * 16 + l15][quad * 8];
        #pragma unroll
        for (int i = 0; i < 4; ++i)
            #pragma unroll
            for (int j = 0; j < 4; ++j)
                acc[i][j] = __builtin_amdgcn_mfma_f32_16x16x32_f16(af[i], bf[j], acc[i][j], 0, 0, 0);
        __syncthreads();
    }

    // epilogue: bounce 64-row halves through LDS (fp32), bias+relu+cvt, coalesced store
    const int trow = tid >> 2, coff = (tid & 3) * 32;
    float bcol[32];
    if (!BIASROW) {
        #pragma unroll
        for (int i = 0; i < 8; ++i)
            *(float4*)&bcol[i * 4] = *(const float4*)&bias[n0 + coff + i * 4];
    }
    #pragma unroll
    for (int p = 0; p < 2; ++p) {
        if (p) __syncthreads();
        if ((wave >> 1) == p) {
            #pragma unroll
            for (int mi = 0; mi < 4; ++mi)
                #pragma unroll
                for (int ni = 0; ni < 4; ++ni)
                    #pragma unroll
                    for (int r = 0; r < 4; ++r)
                        Ct[mi * 16 + quad * 4 + r][wn + ni * 16 + l15] = acc[mi][ni][r];
        }
        __syncthreads();
        float brow = 0.f;
        if (BIASROW) brow = bias[m0 + p * 64 + trow];
        float vv[32];
        #pragma unroll
        for (int i = 0; i < 8; ++i) *(float4*)&vv[i * 4] = *(float4*)&Ct[trow][coff + i * 4];
        _Float16 o[32];
        #pragma unroll
        for (int i = 0; i < 32; ++i) {
            float v = vv[i] + (BIASROW ? brow : bcol[i]);
            if (RELU) v = fmaxf(v, 0.f);
            o[i] = (_Float16)v;
        }
        _Float16* dst = C + (size_t)(m0 + p * 64 + trow) * N + n0 + coff;
        #pragma unroll
        for (int i = 0; i < 4; ++i) *(float4*)(dst + i * 8) = *(float4*)&o[i * 8];
    }
}

// Forward LSTM scan v6: NB=2 batch interleave to hide the MALL exchange.
// 64 pairs x 2 halves = 128 blocks. Block (p, is_hi) runs batches gb0=2p,
// gb1=2p+1 over units [is_hi*128, is_hi*128+128) with ONE shared weight set
// (w_hh is batch-independent: 64 half2 VGPRs/thread, same as v5).
// Per t-step, 3 phases:
//   A: all dot(g0)            || wave15 polls partner h_g1(t-1) (published a
//                                full phase ago -> first poll hits)
//   B: all dot(g1)            || wave0 act(g0)+publish
//   C: wave1 act(g1)+publish  || wave15 polls partner h_g0(t)  (published in
//                                B -> >=1 phase of slack)
// Each batch's publish->poll MALL roundtrip (the ~3300cy/step stall of v5,
// cf. WRITE_SIZE=74MB = write-through publishes) overlaps the OTHER batch's
// 512cy dot + act instead of sitting serially between act and the next dot.
// Poll graph is acyclic (C-poll <- partner B-publish <- partner A-poll <-
// my previous C-publish): deadlock-free; all 128 blocks trivially resident.
// Tagging identical to v5 (monotone tags 1..511; 0xAA poison never matches;
// stale tags from a prior run carry identical h values -> benign).
__global__ __launch_bounds__(1024, 4) void lstm_scan6(
    const _Float16* __restrict__ xg, const float* __restrict__ whh,
    float* __restrict__ out, unsigned long long* __restrict__ xb)
{
    const int tid = threadIdx.x;
    const int bid = blockIdx.x;                 // 128 blocks
    const int is_hi = (bid >= 64) ? 1 : 0;
    const int p = is_hi ? bid - 64 : bid;       // pair id
    const int gb0 = 2 * p, gb1 = 2 * p + 1;     // the two batches
    const int q4 = tid >> 8;                    // K-quarter (wave-uniform)
    const int s = tid & 255;
    const int u = s & 127;
    const int rowA = (s >> 7) * 256 + is_hi * 128 + u;  // gate 0/1 row
    const int rowB = rowA + 512;                        // gate 2/3 row
    const int wv = tid >> 6, l = tid & 63;

    __shared__ __align__(16) unsigned int hsh[2][128];  // per-batch h (256 f16)
    __shared__ __align__(16) float psh[2][2048];        // per-batch [quarter][512]

    half2_t wA[32], wB[32];
    {
        const float4* pa = (const float4*)(whh + (size_t)rowA * 256 + q4 * 64);
        const float4* pb = (const float4*)(whh + (size_t)rowB * 256 + q4 * 64);
        #pragma unroll
        for (int k = 0; k < 16; ++k) {
            float4 a = pa[k], b = pb[k];
            wA[2 * k + 0] = half2_t{(_Float16)a.x, (_Float16)a.y};
            wA[2 * k + 1] = half2_t{(_Float16)a.z, (_Float16)a.w};
            wB[2 * k + 0] = half2_t{(_Float16)b.x, (_Float16)b.y};
            wB[2 * k + 1] = half2_t{(_Float16)b.z, (_Float16)b.w};
        }
    }
    if (tid < 256) hsh[tid >> 7][tid & 127] = 0u;

    const _Float16* xgb0 = xg + (size_t)gb0 * TT * GG;
    const _Float16* xgb1 = xg + (size_t)gb1 * TT * GG;
    float x0A = 0.f, x0B = 0.f, x1A = 0.f, x1B = 0.f;
    if (q4 == 1) {   // q4==1 (waves 4-7): keeps prefetch off act waves 0/1
        x0A = (float)xgb0[rowA]; x0B = (float)xgb0[rowB];
        x1A = (float)xgb1[rowA]; x1B = (float)xgb1[rowB];
    }
    float c0 = 0.f, c1 = 0.f, hk0 = 0.f, hk1 = 0.f;  // act-wave lane state
    __syncthreads();

    auto dot_phase = [&](int bb, float vA, float vB) {
        float aA0 = 0.f, aA1 = 0.f, aB0 = 0.f, aB1 = 0.f;
        const float4* hp = (const float4*)&hsh[bb][0] + q4 * 8;
        #pragma unroll
        for (int kk = 0; kk < 8; ++kk) {
            const float4 hv = hp[kk];   // wave-uniform address -> broadcast
            const half2_t h0 = __builtin_bit_cast(half2_t, hv.x);
            const half2_t h1 = __builtin_bit_cast(half2_t, hv.y);
            const half2_t h2 = __builtin_bit_cast(half2_t, hv.z);
            const half2_t h3 = __builtin_bit_cast(half2_t, hv.w);
            aA0 = fdot2_(wA[4 * kk + 0], h0, aA0);
            aA1 = fdot2_(wA[4 * kk + 1], h1, aA1);
            aA0 = fdot2_(wA[4 * kk + 2], h2, aA0);
            aA1 = fdot2_(wA[4 * kk + 3], h3, aA1);
            aB0 = fdot2_(wB[4 * kk + 0], h0, aB0);
            aB1 = fdot2_(wB[4 * kk + 1], h1, aB1);
            aB0 = fdot2_(wB[4 * kk + 2], h2, aB0);
            aB1 = fdot2_(wB[4 * kk + 3], h3, aB1);
        }
        psh[bb][q4 * 512 + s]       = aA0 + aA1 + vA;
        psh[bb][q4 * 512 + 256 + s] = aB0 + aB1 + vB;
    };

    auto act_publish = [&](int bb, int gbb, int t) {
        float2 gate[4];
        #pragma unroll
        for (int gg = 0; gg < 4; ++gg) {
            float2 sum = {0.f, 0.f};
            #pragma unroll
            for (int qq = 0; qq < 4; ++qq) {
                const float2 v = *(const float2*)&psh[bb][qq * 512 + gg * 128 + 2 * l];
                sum.x += v.x; sum.y += v.y;
            }
            gate[gg] = sum;
        }
        const float i0 = sigf(gate[0].x), i1 = sigf(gate[0].y);
        const float f0 = sigf(gate[1].x), f1 = sigf(gate[1].y);
        const float q0 = tanhf_(gate[2].x), q1 = tanhf_(gate[2].y);
        const float o0 = sigf(gate[3].x), o1 = sigf(gate[3].y);
        c0 = f0 * c0 + i0 * q0;  hk0 = o0 * tanhf_(c0);
        c1 = f1 * c1 + i1 * q1;  hk1 = o1 * tanhf_(c1);
        const unsigned int u0 =
            (unsigned int)__builtin_bit_cast(unsigned short, (_Float16)hk0);
        const unsigned int u1 =
            (unsigned int)__builtin_bit_cast(unsigned short, (_Float16)hk1);
        if (t < TT - 1) {   // publish first: partner's poll is the long pole
            const unsigned int tg = (unsigned int)(t + 1) << 16;
            const unsigned long long pk =
                ((unsigned long long)(tg | u1) << 32) | (unsigned long long)(tg | u0);
            __hip_atomic_store(&xb[((size_t)gbb * 2 + is_hi) * 64 + l], pk,
                               __ATOMIC_RELAXED, __HIP_MEMORY_SCOPE_AGENT);
            asm volatile("" ::: "memory");
        }
        hsh[bb][is_hi * 64 + l] = u0 | (u1 << 16);
    };

    auto poll_partner = [&](int bb, int gbb, unsigned int tag) {
        const unsigned long long* src = &xb[((size_t)gbb * 2 + (1 - is_hi)) * 64 + l];
        unsigned long long v;
        for (;;) {
            v = __hip_atomic_load(src, __ATOMIC_RELAXED, __HIP_MEMORY_SCOPE_AGENT);
            if ((((v >> 16) & 0xFFFFu) == tag) && ((unsigned)(v >> 48) == tag)) break;
            __builtin_amdgcn_s_sleep(1);
        }
        hsh[bb][(1 - is_hi) * 64 + l] =
            (unsigned int)(v & 0xFFFFu) | ((unsigned int)((v >> 32) & 0xFFFFu) << 16);
    };

    for (int t = 0; t < TT; ++t) {
        const float v0A = x0A, v0B = x0B, v1A = x1A, v1B = x1B;
        if (q4 == 1 && t < TT - 1) {   // prefetch t+1 behind the whole iter
            x0A = (float)xgb0[(size_t)(t + 1) * GG + rowA];
            x0B = (float)xgb0[(size_t)(t + 1) * GG + rowB];
            x1A = (float)xgb1[(size_t)(t + 1) * GG + rowA];
            x1B = (float)xgb1[(size_t)(t + 1) * GG + rowB];
        }
        // --- Phase A: dot(g0); wave15 gathers partner h_g1(t-1)
        if (wv == 15 && t > 0) poll_partner(1, gb1, (unsigned int)t);
        dot_phase(0, v0A, v0B);
        __syncthreads();   // psh[0] staged; hsh[1] partner half landed

        // --- Phase B: dot(g1); wave0 act(g0)+publish
        if (wv == 0) act_publish(0, gb0, t);
        dot_phase(1, v1A, v1B);
        __syncthreads();   // psh[1] staged; hsh[0] own half landed

        // --- Phase C: wave1 act(g1)+publish; wave15 gathers partner h_g0(t)
        if (wv == 1) act_publish(1, gb1, t);
        if (wv == 15 && t < TT - 1) poll_partner(0, gb0, (unsigned int)(t + 1));
        __syncthreads();   // hsh[1] own + hsh[0] partner halves landed
    }
    if (wv == 0) {
        out[(size_t)gb0 * 512 + is_hi * 128 + 2 * l + 0] = hk0;
        out[(size_t)gb0 * 512 + is_hi * 128 + 2 * l + 1] = hk1;
    }
    if (wv == 1) {
        out[(size_t)gb1 * 512 + is_hi * 128 + 2 * l + 0] = hk0;
        out[(size_t)gb1 * 512 + is_hi * 128 + 2 * l + 1] = hk1;
    }
}

// Backward-direction LSTM last step (h=c=0): needs only seq[:,T-1,:].
__global__ __launch_bounds__(256) void lstm_back_last(
    const _Float16* __restrict__ y2h, const float* __restrict__ wih,
    const float* __restrict__ bih, const float* __restrict__ bhh,
    float* __restrict__ out)
{
    const int b = blockIdx.x;
    const int t = threadIdx.x;
    __shared__ float s[256];
    s[t] = (float)y2h[(size_t)b * (HID * TT) + (TT - 1) * HID + t];
    __syncthreads();
    float acc[4];
    #pragma unroll
    for (int q = 0; q < 4; ++q) acc[q] = bih[t + q * 256] + bhh[t + q * 256];
    #pragma unroll
    for (int q = 0; q < 4; ++q) {
        const float* w = wih + (size_t)(t + q * 256) * 256;
        float a = acc[q];
        for (int k = 0; k < 256; k += 4) {
            const float4 w4 = *(const float4*)&w[k];
            const float4 h4 = *(const float4*)&s[k];
            a += w4.x * h4.x; a += w4.y * h4.y;
            a += w4.z * h4.z; a += w4.w * h4.w;
        }
        acc[q] = a;
    }
    const float i = sigf(acc[0]);
    const float g = tanhf_(acc[2]), o = sigf(acc[3]);
    const float c = i * g;           // c_prev = 0, forget path vanishes
    const float h = o * tanhf_(c);
    out[(size_t)b * 512 + 256 + t] = h;
}

extern "C" void kernel_launch(void* const* d_in, const int* in_sizes, int n_in,
                              void* d_out, int out_size, void* d_ws, size_t ws_size,
                              hipStream_t stream) {
    const float* x      = (const float*)d_in[0];
    const float* w1     = (const float*)d_in[1];
    const float* b1     = (const float*)d_in[2];
    const float* w2     = (const float*)d_in[3];
    const float* b2     = (const float*)d_in[4];
    const float* w_ih_f = (const float*)d_in[5];
    const float* w_hh_f = (const float*)d_in[6];
    const float* b_ih_f = (const float*)d_in[7];
    const float* b_hh_f = (const float*)d_in[8];
    const float* w_ih_b = (const float*)d_in[9];
    // d_in[10] = w_hh_b: provably unused (only first reversed step reaches output)
    const float* b_ih_b = (const float*)d_in[11];
    const float* b_hh_b = (const float*)d_in[12];
    float* out = (float*)d_out;

    // Workspace layout (bytes):
    //   xgh  f16 [65536][1024] :         0 .. 134217728
    //   xt   f16 [128][512][512]: 134217728 .. 201326592
    //   y1t  f16 [128][512][256]: 201326592 .. 234881024   (= y1^T per batch)
    //   y2h  f16 [128][256][512]: 234881024 .. 268435456   (canonical = seq flat)
    //   w1h  f16 131072        : 268435456 .. 268697600
    //   w2h  f16 65536         : 268697600 .. 268828672
    //   wihh f16 262144        : 268828672 .. 269352960
    //   bsum f32 1024          : 269352960 .. 269357056
    //   xb   u64 16384         : 269357056 .. 269488128   (tagged h exchange)
    char* ws = (char*)d_ws;
    _Float16* xgh  = (_Float16*)(ws);
    _Float16* xt   = (_Float16*)(ws + 134217728);
    _Float16* y1t  = (_Float16*)(ws + 201326592);
    _Float16* y2h  = (_Float16*)(ws + 234881024);
    _Float16* w1h  = (_Float16*)(ws + 268435456);
    _Float16* w2h  = (_Float16*)(ws + 268697600);
    _Float16* wihh = (_Float16*)(ws + 268828672);
    float*    bsum = (float*)   (ws + 269352960);
    unsigned long long* xb = (unsigned long long*)(ws + 269357056);

    prep_cast<<<1024, 256, 0, stream>>>(w1, w2, w_ih_f, b_ih_f, b_hh_f,
                                        w1h, w2h, wihh, bsum);
    cast_transpose_x<<<dim3(8, 8, BATCH), 256, 0, stream>>>(x, xt);
    // conv1: y1t[b][t][m1] = relu( xt[b][t][:] . w1h[m1][:] + b1[m1] )   (bias on col)
    mfma_nt<1, 0><<<dim3(2, 4, BATCH), 256, 0, stream>>>(
        xt, w1h, b1, y1t, 512, 256, 512, 512L * 512, 0, 512L * 256);
    // conv2: y2h[b][m2][t] = relu( w2h[m2][:] . y1t[b][t][:] + b2[m2] )  (bias on row)
    mfma_nt<1, 1><<<dim3(4, 2, BATCH), 256, 0, stream>>>(
        w2h, y1t, b2, y2h, 256, 512, 256, 0, 512L * 256, 256L * 512);
    // xg: xgh[r][g] = y2h-flat[r][:] . wihh[g][:] + bsum[g]              (bias on col)
    mfma_nt<0, 0><<<dim3(8, 512, 1), 256, 0, stream>>>(
        y2h, wihh, bsum, xgh, 65536, 1024, 256, 0, 0, 0);
    // backward last step (writes out[:, 256:512))
    lstm_back_last<<<BATCH, 256, 0, stream>>>(y2h, w_ih_b, b_ih_b, b_hh_b, out);
    // forward scan, NB=2 batch-interleaved (writes out[:, 0:256))
    lstm_scan6<<<128, 1024, 0, stream>>>(xgh, w_hh_f, out, xb);
}

// Round 2
// 1422.089 us; speedup vs baseline: 1.1462x; 1.1462x over previous
//
#include <hip/hip_runtime.h>
#include <math.h>

// Sizes fixed by the problem
#define BATCH 128
#define TT 512      // time steps
#define CIN 512
#define HID 256
#define GG 1024     // 4*HID

typedef _Float16 half2_t __attribute__((ext_vector_type(2)));
typedef _Float16 half8_t __attribute__((ext_vector_type(8)));
typedef float f32x4_t __attribute__((ext_vector_type(4)));

__device__ __forceinline__ float sigf(float x) { return 1.f / (1.f + __expf(-x)); }
__device__ __forceinline__ float tanhf_(float x) {
    float a = fabsf(x);
    float e = __expf(-2.f * a);
    float r = (1.f - e) / (1.f + e);
    return copysignf(r, x);
}
__device__ __forceinline__ float fdot2_(half2_t a, half2_t b, float c) {
#if __has_builtin(__builtin_amdgcn_fdot2)
    return __builtin_amdgcn_fdot2(a, b, c, false);
#else
    return c + (float)a.x * (float)b.x + (float)a.y * (float)b.y;
#endif
}

// Tiny prep: cast w1/w2/w_ih_f to f16, sum LSTM biases. grid 1024x256.
__global__ void prep_cast(const float* __restrict__ w1, const float* __restrict__ w2,
                          const float* __restrict__ wih, const float* __restrict__ bih,
                          const float* __restrict__ bhh,
                          _Float16* __restrict__ w1h, _Float16* __restrict__ w2h,
                          _Float16* __restrict__ wihh, float* __restrict__ bsum)
{
    const int i = blockIdx.x * 256 + threadIdx.x;
    if (i < 131072) w1h[i] = (_Float16)w1[i];
    if (i < 65536)  w2h[i] = (_Float16)w2[i];
    if (i < 262144) wihh[i] = (_Float16)wih[i];
    if (i < 1024)   bsum[i] = bih[i] + bhh[i];
}

// x[b][c=512][t=512] fp32 -> xt[b][t][c] f16 (64x64 LDS tiles, coalesced both sides)
__global__ __launch_bounds__(256) void cast_transpose_x(
    const float* __restrict__ x, _Float16* __restrict__ xt)
{
    const int b = blockIdx.z, c0 = blockIdx.y * 64, t0 = blockIdx.x * 64;
    __shared__ float tl[64][68];
    const float* xb = x + (size_t)b * CIN * TT;
    const int tid = threadIdx.x;
    const int lt = (tid & 15) * 4, lc = tid >> 4;
    #pragma unroll
    for (int r = 0; r < 4; ++r) {
        const int c = lc + r * 16;
        float4 v = *(const float4*)(xb + (size_t)(c0 + c) * TT + t0 + lt);
        tl[c][lt] = v.x; tl[c][lt + 1] = v.y; tl[c][lt + 2] = v.z; tl[c][lt + 3] = v.w;
    }
    __syncthreads();
    const int trow = tid >> 2, coff = (tid & 3) * 16;
    _Float16 o[16];
    #pragma unroll
    for (int i = 0; i < 16; ++i) o[i] = (_Float16)tl[coff + i][trow];
    _Float16* dst = xt + (size_t)b * TT * CIN + (size_t)(t0 + trow) * CIN + c0 + coff;
    *(float4*)dst = *(float4*)&o[0];
    *(float4*)(dst + 8) = *(float4*)&o[8];
}

// C[M,N](f16) = op( A[M,K]f16 . B[N,K]f16^T + bias ), K%32==0, M%128==0, N%128==0.
// 128x128 tile, 256 thr = 4 waves of 64x64, v_mfma_f32_16x16x32_f16.
// A/B-frag idx=lane&15, k=quad*8+j; D row=quad*4+reg, col=lane&15 (verified).
template <int RELU, int BIASROW>
__global__ __launch_bounds__(256, 4) void mfma_nt(
    const _Float16* __restrict__ A, const _Float16* __restrict__ B,
    const float* __restrict__ bias, _Float16* __restrict__ C,
    int M, int N, int K, long sA, long sB, long sC)
{
    __shared__ __align__(16) char smem[34816];
    _Float16 (*As)[40] = (_Float16(*)[40])smem;
    _Float16 (*Bs)[40] = (_Float16(*)[40])(smem + 10240);
    float (*Ct)[132] = (float(*)[132])smem;   // 64 x 132 fp32 (union w/ stage)

    const int nb = blockIdx.z;
    A += (size_t)nb * sA; B += (size_t)nb * sB; C += (size_t)nb * sC;
    const int m0 = blockIdx.y * 128, n0 = blockIdx.x * 128;
    const int tid = threadIdx.x;
    const int wave = tid >> 6, lane = tid & 63;
    const int quad = lane >> 4, l15 = lane & 15;
    const int wm = (wave >> 1) * 64, wn = (wave & 1) * 64;
    const int srow = tid >> 1, sko = (tid & 1) * 16;   // staging map

    f32x4_t acc[4][4];
    const f32x4_t zz = {0.f, 0.f, 0.f, 0.f};
    #pragma unroll
    for (int i = 0; i < 4; ++i)
        #pragma unroll
        for (int j = 0; j < 4; ++j) acc[i][j] = zz;

    for (int k0 = 0; k0 < K; k0 += 32) {
        {   // stage A,B tiles: 128 rows x 32 k each; thread = 16 f16 per tile
            const float4* ga = (const float4*)(A + (size_t)(m0 + srow) * K + k0 + sko);
            float4 a0 = ga[0], a1 = ga[1];
            const float4* gb = (const float4*)(B + (size_t)(n0 + srow) * K + k0 + sko);
            float4 b0 = gb[0], b1 = gb[1];
            *(float4*)&As[srow][sko] = a0; *(float4*)&As[srow][sko + 8] = a1;
            *(float4*)&Bs[srow][sko] = b0; *(float4*)&Bs[srow][sko + 8] = b1;
        }
        __syncthreads();
        half8_t af[4], bf[4];
        #pragma unroll
        for (int i = 0; i < 4; ++i) af[i] = *(const half8_t*)&As[wm + i * 16 + l15][quad * 8];
        #pragma unroll
        for (int j = 0; j < 4; ++j) bf[j] = *(const half8_t*)&Bs[wn + j * 16 + l15][quad * 8];
        #pragma unroll
        for (int i = 0; i < 4; ++i)
            #pragma unroll
            for (int j = 0; j < 4; ++j)
                acc[i][j] = __builtin_amdgcn_mfma_f32_16x16x32_f16(af[i], bf[j], acc[i][j], 0, 0, 0);
        __syncthreads();
    }

    // epilogue: bounce 64-row halves through LDS (fp32), bias+relu+cvt, coalesced store
    const int trow = tid >> 2, coff = (tid & 3) * 32;
    float bcol[32];
    if (!BIASROW) {
        #pragma unroll
        for (int i = 0; i < 8; ++i)
            *(float4*)&bcol[i * 4] = *(const float4*)&bias[n0 + coff + i * 4];
    }
    #pragma unroll
    for (int p = 0; p < 2; ++p) {
        if (p) __syncthreads();
        if ((wave >> 1) == p) {
            #pragma unroll
            for (int mi = 0; mi < 4; ++mi)
                #pragma unroll
                for (int ni = 0; ni < 4; ++ni)
                    #pragma unroll
                    for (int r = 0; r < 4; ++r)
                        Ct[mi * 16 + quad * 4 + r][wn + ni * 16 + l15] = acc[mi][ni][r];
        }
        __syncthreads();
        float brow = 0.f;
        if (BIASROW) brow = bias[m0 + p * 64 + trow];
        float vv[32];
        #pragma unroll
        for (int i = 0; i < 8; ++i) *(float4*)&vv[i * 4] = *(float4*)&Ct[trow][coff + i * 4];
        _Float16 o[32];
        #pragma unroll
        for (int i = 0; i < 32; ++i) {
            float v = vv[i] + (BIASROW ? brow : bcol[i]);
            if (RELU) v = fmaxf(v, 0.f);
            o[i] = (_Float16)v;
        }
        _Float16* dst = C + (size_t)(m0 + p * 64 + trow) * N + n0 + coff;
        #pragma unroll
        for (int i = 0; i < 4; ++i) *(float4*)(dst + i * 8) = *(float4*)&o[i * 8];
    }
}

// Forward LSTM scan v7: ONE block per batch -> zero cross-block traffic.
// v5/v6 post-mortem: the ~3300cy/step MALL publish->poll roundtrip (2-block
// unit split) was the critical path; batches were already parallel across
// blocks, so v6's interleave couldn't help. v7 removes the exchange:
// 1024 thr = (q4 = K-quarter, s = unit). Thread (q4,s) owns gate rows
// s (i), s+256 (f), s+512 (g) in 96 half2 VGPRs (quarter q4: 64 K each)
// and streams gate-o row s+768 from a 128KB LDS tile (the 512KB f16 weight
// matrix = 3/4 regs + 1/4 LDS; gfx950 unified 128-reg budget @4 waves/SIMD).
// wlds XOR-swizzle: row stride 512B == bank 0 for all lanes, so granule g
// (16B) of row s is stored at s*512 + ((g ^ (s&7))<<4) -> each 8-lane group
// covers all 32 banks -> conflict-free ds_read_b128 (check SQ_LDS_BANK_CONFLICT).
// Step: dot (128 fdot2/thr ~1024cy VALU, LDS stream ~1170cy overlapped)
// -> B1 -> 256 act threads (gates + xg from double-buffered xgsh staged by
// waves 12-15) -> B2. No atomics, no polls, no hang risk.
__global__ __launch_bounds__(1024, 4) void lstm_scan7(
    const _Float16* __restrict__ xg, const float* __restrict__ whh,
    float* __restrict__ out)
{
    __shared__ __align__(16) _Float16 wlds[256 * 256];   // 128 KB o-gate weights (swizzled)
    __shared__ __align__(16) float psh[4096];            // 16 KB partials [q][1024 rows]
    __shared__ __align__(16) _Float16 xgsh[2][1024];     // 4 KB xg double buffer
    __shared__ __align__(16) _Float16 hshh[256];         // h (f16)

    const int tid = threadIdx.x;
    const int b   = blockIdx.x;
    const int q4  = tid >> 8;        // K-quarter (wave-uniform)
    const int s   = tid & 255;       // unit
    const _Float16* xgb = xg + (size_t)b * TT * GG;

    // ---- init: o-gate rows 768..1023 -> LDS, f32->f16, swizzled store
    {
        const int sr = tid >> 2, c4 = tid & 3;
        const float* wr = whh + (size_t)(768 + sr) * 256;
        #pragma unroll
        for (int j = 0; j < 8; ++j) {
            const int g = c4 * 8 + j;            // 16B granule index in row
            const float4 w0 = *(const float4*)&wr[g * 8 + 0];
            const float4 w1 = *(const float4*)&wr[g * 8 + 4];
            float4 pk;
            half2_t* pp = (half2_t*)&pk;
            pp[0] = half2_t{(_Float16)w0.x, (_Float16)w0.y};
            pp[1] = half2_t{(_Float16)w0.z, (_Float16)w0.w};
            pp[2] = half2_t{(_Float16)w1.x, (_Float16)w1.y};
            pp[3] = half2_t{(_Float16)w1.z, (_Float16)w1.w};
            *(float4*)((char*)wlds + sr * 512 + ((g ^ (sr & 7)) << 4)) = pk;
        }
    }
    // ---- reg weights: rows s (i), s+256 (f), s+512 (g), K in [64*q4, 64*q4+64)
    half2_t wI[32], wF[32], wGt[32];
    {
        const float4* pi = (const float4*)(whh + (size_t)(s)*256 + q4 * 64);
        const float4* pf = (const float4*)(whh + (size_t)(s + 256) * 256 + q4 * 64);
        const float4* pg = (const float4*)(whh + (size_t)(s + 512) * 256 + q4 * 64);
        #pragma unroll
        for (int k = 0; k < 16; ++k) {
            const float4 a = pi[k];
            wI[2 * k + 0] = half2_t{(_Float16)a.x, (_Float16)a.y};
            wI[2 * k + 1] = half2_t{(_Float16)a.z, (_Float16)a.w};
            const float4 f = pf[k];
            wF[2 * k + 0] = half2_t{(_Float16)f.x, (_Float16)f.y};
            wF[2 * k + 1] = half2_t{(_Float16)f.z, (_Float16)f.w};
            const float4 g = pg[k];
            wGt[2 * k + 0] = half2_t{(_Float16)g.x, (_Float16)g.y};
            wGt[2 * k + 1] = half2_t{(_Float16)g.z, (_Float16)g.w};
        }
    }
    if (tid < 128) ((unsigned int*)hshh)[tid] = 0u;      // h0 = 0
    if (q4 == 3) {                                       // preload xg[0]
        *(uint2*)&xgsh[0][4 * s] = *(const uint2*)&xgb[4 * s];
    }
    float c = 0.f, hlast = 0.f;                          // act-thread state
    __syncthreads();

    const float4* hp = (const float4*)hshh + q4 * 8;     // this quarter's h (broadcast)
    const char* wob = (const char*)wlds + s * 512 + q4 * 128;
    const int sw3 = s & 7;

    for (int t = 0; t < TT; ++t) {
        if (q4 == 3 && t + 1 < TT) {   // stage xg[t+1]; latency hides under dot
            *(uint2*)&xgsh[(t + 1) & 1][4 * s] =
                *(const uint2*)&xgb[(size_t)(t + 1) * GG + 4 * s];
        }
        float aI = 0.f, aF = 0.f, aG = 0.f, aO = 0.f;
        #pragma unroll
        for (int kk = 0; kk < 8; ++kk) {
            const float4 hv = hp[kk];                    // wave-uniform -> broadcast
            const half2_t h0 = __builtin_bit_cast(half2_t, hv.x);
            const half2_t h1 = __builtin_bit_cast(half2_t, hv.y);
            const half2_t h2 = __builtin_bit_cast(half2_t, hv.z);
            const half2_t h3 = __builtin_bit_cast(half2_t, hv.w);
            const float4 wv = *(const float4*)(wob + ((kk ^ sw3) << 4));  // swizzled o-row
            const half2_t o0 = __builtin_bit_cast(half2_t, wv.x);
            const half2_t o1 = __builtin_bit_cast(half2_t, wv.y);
            const half2_t o2 = __builtin_bit_cast(half2_t, wv.z);
            const half2_t o3 = __builtin_bit_cast(half2_t, wv.w);
            aI = fdot2_(wI[4 * kk + 0], h0, aI);
            aI = fdot2_(wI[4 * kk + 1], h1, aI);
            aI = fdot2_(wI[4 * kk + 2], h2, aI);
            aI = fdot2_(wI[4 * kk + 3], h3, aI);
            aF = fdot2_(wF[4 * kk + 0], h0, aF);
            aF = fdot2_(wF[4 * kk + 1], h1, aF);
            aF = fdot2_(wF[4 * kk + 2], h2, aF);
            aF = fdot2_(wF[4 * kk + 3], h3, aF);
            aG = fdot2_(wGt[4 * kk + 0], h0, aG);
            aG = fdot2_(wGt[4 * kk + 1], h1, aG);
            aG = fdot2_(wGt[4 * kk + 2], h2, aG);
            aG = fdot2_(wGt[4 * kk + 3], h3, aG);
            aO = fdot2_(o0, h0, aO);
            aO = fdot2_(o1, h1, aO);
            aO = fdot2_(o2, h2, aO);
            aO = fdot2_(o3, h3, aO);
        }
        psh[q4 * 1024 + s]       = aI;
        psh[q4 * 1024 + s + 256] = aF;
        psh[q4 * 1024 + s + 512] = aG;
        psh[q4 * 1024 + s + 768] = aO;
        __syncthreads();               // B1: partials staged, h reads done
        if (tid < 256) {               // waves 0-3 finish unit s
            const int cur = t & 1;
            const float gi = psh[s] + psh[1024 + s] + psh[2048 + s] + psh[3072 + s]
                             + (float)xgsh[cur][s];
            const float gf = psh[s + 256] + psh[1280 + s] + psh[2304 + s] + psh[3328 + s]
                             + (float)xgsh[cur][s + 256];
            const float gq = psh[s + 512] + psh[1536 + s] + psh[2560 + s] + psh[3584 + s]
                             + (float)xgsh[cur][s + 512];
            const float go = psh[s + 768] + psh[1792 + s] + psh[2816 + s] + psh[3840 + s]
                             + (float)xgsh[cur][s + 768];
            const float iv = sigf(gi), fv = sigf(gf), gv = tanhf_(gq), ov = sigf(go);
            c = fv * c + iv * gv;
            hlast = ov * tanhf_(c);
            hshh[s] = (_Float16)hlast;
        }
        __syncthreads();               // B2: new h visible to all
    }
    if (tid < 256) out[(size_t)b * 512 + s] = hlast;
}

// Backward-direction LSTM last step (h=c=0): needs only seq[:,T-1,:].
__global__ __launch_bounds__(256) void lstm_back_last(
    const _Float16* __restrict__ y2h, const float* __restrict__ wih,
    const float* __restrict__ bih, const float* __restrict__ bhh,
    float* __restrict__ out)
{
    const int b = blockIdx.x;
    const int t = threadIdx.x;
    __shared__ float s[256];
    s[t] = (float)y2h[(size_t)b * (HID * TT) + (TT - 1) * HID + t];
    __syncthreads();
    float acc[4];
    #pragma unroll
    for (int q = 0; q < 4; ++q) acc[q] = bih[t + q * 256] + bhh[t + q * 256];
    #pragma unroll
    for (int q = 0; q < 4; ++q) {
        const float* w = wih + (size_t)(t + q * 256) * 256;
        float a = acc[q];
        for (int k = 0; k < 256; k += 4) {
            const float4 w4 = *(const float4*)&w[k];
            const float4 h4 = *(const float4*)&s[k];
            a += w4.x * h4.x; a += w4.y * h4.y;
            a += w4.z * h4.z; a += w4.w * h4.w;
        }
        acc[q] = a;
    }
    const float i = sigf(acc[0]);
    const float g = tanhf_(acc[2]), o = sigf(acc[3]);
    const float c = i * g;           // c_prev = 0, forget path vanishes
    const float h = o * tanhf_(c);
    out[(size_t)b * 512 + 256 + t] = h;
}

extern "C" void kernel_launch(void* const* d_in, const int* in_sizes, int n_in,
                              void* d_out, int out_size, void* d_ws, size_t ws_size,
                              hipStream_t stream) {
    const float* x      = (const float*)d_in[0];
    const float* w1     = (const float*)d_in[1];
    const float* b1     = (const float*)d_in[2];
    const float* w2     = (const float*)d_in[3];
    const float* b2     = (const float*)d_in[4];
    const float* w_ih_f = (const float*)d_in[5];
    const float* w_hh_f = (const float*)d_in[6];
    const float* b_ih_f = (const float*)d_in[7];
    const float* b_hh_f = (const float*)d_in[8];
    const float* w_ih_b = (const float*)d_in[9];
    // d_in[10] = w_hh_b: provably unused (only first reversed step reaches output)
    const float* b_ih_b = (const float*)d_in[11];
    const float* b_hh_b = (const float*)d_in[12];
    float* out = (float*)d_out;

    // Workspace layout (bytes):
    //   xgh  f16 [65536][1024] :         0 .. 134217728
    //   xt   f16 [128][512][512]: 134217728 .. 201326592
    //   y1t  f16 [128][512][256]: 201326592 .. 234881024   (= y1^T per batch)
    //   y2h  f16 [128][256][512]: 234881024 .. 268435456   (canonical = seq flat)
    //   w1h  f16 131072        : 268435456 .. 268697600
    //   w2h  f16 65536         : 268697600 .. 268828672
    //   wihh f16 262144        : 268828672 .. 269352960
    //   bsum f32 1024          : 269352960 .. 269357056
    char* ws = (char*)d_ws;
    _Float16* xgh  = (_Float16*)(ws);
    _Float16* xt   = (_Float16*)(ws + 134217728);
    _Float16* y1t  = (_Float16*)(ws + 201326592);
    _Float16* y2h  = (_Float16*)(ws + 234881024);
    _Float16* w1h  = (_Float16*)(ws + 268435456);
    _Float16* w2h  = (_Float16*)(ws + 268697600);
    _Float16* wihh = (_Float16*)(ws + 268828672);
    float*    bsum = (float*)   (ws + 269352960);

    prep_cast<<<1024, 256, 0, stream>>>(w1, w2, w_ih_f, b_ih_f, b_hh_f,
                                        w1h, w2h, wihh, bsum);
    cast_transpose_x<<<dim3(8, 8, BATCH), 256, 0, stream>>>(x, xt);
    // conv1: y1t[b][t][m1] = relu( xt[b][t][:] . w1h[m1][:] + b1[m1] )   (bias on col)
    mfma_nt<1, 0><<<dim3(2, 4, BATCH), 256, 0, stream>>>(
        xt, w1h, b1, y1t, 512, 256, 512, 512L * 512, 0, 512L * 256);
    // conv2: y2h[b][m2][t] = relu( w2h[m2][:] . y1t[b][t][:] + b2[m2] )  (bias on row)
    mfma_nt<1, 1><<<dim3(4, 2, BATCH), 256, 0, stream>>>(
        w2h, y1t, b2, y2h, 256, 512, 256, 0, 512L * 256, 256L * 512);
    // xg: xgh[r][g] = y2h-flat[r][:] . wihh[g][:] + bsum[g]              (bias on col)
    mfma_nt<0, 0><<<dim3(8, 512, 1), 256, 0, stream>>>(
        y2h, wihh, bsum, xgh, 65536, 1024, 256, 0, 0, 0);
    // backward last step (writes out[:, 256:512))
    lstm_back_last<<<BATCH, 256, 0, stream>>>(y2h, w_ih_b, b_ih_b, b_hh_b, out);
    // forward scan v7: one block per batch, no cross-block exchange
    lstm_scan7<<<BATCH, 1024, 0, stream>>>(xgh, w_hh_f, out);
}